// Round 8
// baseline (64.472 us; speedup 1.0000x reference)
//
#include <hip/hip_runtime.h>

#define H 1024
#define W 1024
#define TILE 32
#define SR 40    // hsum rows: TILE + 8 (halo4)
#define SC 36    // hsum cols: TILE + 4
#define VR 36    // vw rows:   TILE + 4
#define VC 36    // vw cols:   TILE + 4

// LDS: s_su 40*36*8 = 11520 B + s_vw 36*36*8 = 10368 B -> 21888 B -> 7 blocks/CU.

__device__ __forceinline__ unsigned bf16rne(float f) {   // fp32 -> bf16 bits (RNE)
    unsigned u = __float_as_uint(f);
    return (u + 0x7FFFu + ((u >> 16) & 1u)) >> 16;
}
__device__ __forceinline__ float bf16lo(unsigned u) { return __uint_as_float(u << 16); }
__device__ __forceinline__ float bf16hi(unsigned u) { return __uint_as_float(u & 0xFFFF0000u); }

__global__ __launch_bounds__(256)
void kuwahara_kernel(const float* __restrict__ inp, float* __restrict__ out) {
    __shared__ float2 s_su[SR][SC];   // (hsum luma, hsum luma^2), halo4 rows
    __shared__ uint2  s_vw[VR][VC];   // bf16 packed: x=(r|g<<16), y=(b|k<<16 -> b|w<<16)

    const int tid = threadIdx.x;
    const int n  = blockIdx.z;
    const int y0 = blockIdx.y * TILE;
    const int x0 = blockIdx.x * TILE;

    const float* __restrict__ pR = inp + ((size_t)(4*n + 0) << 20);
    const float* __restrict__ pG = inp + ((size_t)(4*n + 1) << 20);
    const float* __restrict__ pB = inp + ((size_t)(4*n + 2) << 20);
    const float* __restrict__ pK = inp + ((size_t)(4*n + 3) << 20);

    const int tx  = tid & 31;   // column within tile
    const int tg  = tid >> 5;   // row-group: owns rows 4*tg .. 4*tg+3
    const int gx  = x0 + tx;
    const int pr0 = tg << 2;

    // ---- k at this thread's 4 output pixels (fp32, exact) ----
    float kc[4];
#pragma unroll
    for (int p = 0; p < 4; ++p)
        kc[p] = pK[((y0 + pr0 + p) << 10) + gx];

    // ---- stage 1A: fused luma + horizontal 5-sums, zero-redundancy loads ----
    // Wave-local: 10 lanes per row (each owns one 4-px quad); neighbor quad's
    // luma via __shfl_down. 6 rows/wave, 24 rows/pass, 2 passes cover 40 rows.
    {
        const int lane = tid & 63;
        const int wid  = tid >> 6;
        const int rloc = lane / 10;            // 0..5 active, 6 idle
        const int qq   = lane - rloc * 10;     // quad index 0..9
#pragma unroll
        for (int pass = 0; pass < 2; ++pass) {
            int row = pass * 24 + wid * 6 + rloc;
            bool act = (rloc < 6) && (row < SR);
            float l0 = 0.f, l1 = 0.f, l2 = 0.f, l3 = 0.f;
            if (act) {
                int gy  = y0 - 4 + row;
                int cy  = min(max(gy, 0), H - 1);
                int gcs = x0 - 4 + (qq << 2);
                const int base = cy << 10;
                float rr[4], gg[4], bb[4];
                if (gcs >= 0 && gcs <= W - 4) {
                    float4 r4 = *(const float4*)(pR + base + gcs);
                    float4 g4 = *(const float4*)(pG + base + gcs);
                    float4 b4 = *(const float4*)(pB + base + gcs);
                    rr[0]=r4.x; rr[1]=r4.y; rr[2]=r4.z; rr[3]=r4.w;
                    gg[0]=g4.x; gg[1]=g4.y; gg[2]=g4.z; gg[3]=g4.w;
                    bb[0]=b4.x; bb[1]=b4.y; bb[2]=b4.z; bb[3]=b4.w;
                } else {
#pragma unroll
                    for (int e = 0; e < 4; ++e) {
                        int cx = min(max(gcs + e, 0), W - 1);
                        rr[e] = pR[base + cx]; gg[e] = pG[base + cx]; bb[e] = pB[base + cx];
                    }
                }
                bool rowIn = ((unsigned)gy < (unsigned)H);
                float lv[4];
#pragma unroll
                for (int e = 0; e < 4; ++e) {
                    bool colIn = ((unsigned)(gcs + e) < (unsigned)W);
                    lv[e] = (rowIn && colIn)
                        ? fmaf(0.2126f, rr[e], fmaf(0.7152f, gg[e], 0.0722f * bb[e]))
                        : 0.0f;               // zero pad rows AND cols
                }
                l0 = lv[0]; l1 = lv[1]; l2 = lv[2]; l3 = lv[3];
            }
            // neighbor quad's luma (source lanes are active: same row, q+1<=9)
            float l4 = __shfl_down(l0, 1, 64);
            float l5 = __shfl_down(l1, 1, 64);
            float l6 = __shfl_down(l2, 1, 64);
            float l7 = __shfl_down(l3, 1, 64);
            if (act && qq < 9) {
                float s0 = ((l0 + l1) + (l2 + l3)) + l4;
                float s1 = s0 - l0 + l5;
                float s2 = s1 - l1 + l6;
                float s3 = s2 - l2 + l7;
                float m0=l0*l0, m1=l1*l1, m2=l2*l2, m3=l3*l3;
                float m4=l4*l4, m5=l5*l5, m6=l6*l6, m7=l7*l7;
                float u0 = ((m0 + m1) + (m2 + m3)) + m4;
                float u1 = u0 - m0 + m5;
                float u2 = u1 - m1 + m6;
                float u3 = u2 - m2 + m7;
                int c = qq << 2;
                *(float4*)&s_su[row][c]     = make_float4(s0, u0, s1, u1);
                *(float4*)&s_su[row][c + 2] = make_float4(s2, u2, s3, u3);
            }
        }
    }

    // ---- stage 1B: rgbk -> s_vw, bf16-packed, edge-replicated ----
    for (int idx = tid; idx < VR * 9; idx += 256) {
        int j = idx / 9, q = idx - j * 9;
        int gy  = y0 - 2 + j;
        int cy  = min(max(gy, 0), H - 1);
        int gcs = x0 - 2 + (q << 2);
        const int base = cy << 10;
        float rr[4], gg[4], bb[4], kk[4];
        if (gcs >= 0 && gcs <= W - 4) {
            float4 r4 = *(const float4*)(pR + base + gcs);
            float4 g4 = *(const float4*)(pG + base + gcs);
            float4 b4 = *(const float4*)(pB + base + gcs);
            float4 k4 = *(const float4*)(pK + base + gcs);
            rr[0]=r4.x; rr[1]=r4.y; rr[2]=r4.z; rr[3]=r4.w;
            gg[0]=g4.x; gg[1]=g4.y; gg[2]=g4.z; gg[3]=g4.w;
            bb[0]=b4.x; bb[1]=b4.y; bb[2]=b4.z; bb[3]=b4.w;
            kk[0]=k4.x; kk[1]=k4.y; kk[2]=k4.z; kk[3]=k4.w;
        } else {
#pragma unroll
            for (int e = 0; e < 4; ++e) {
                int cx = min(max(gcs + e, 0), W - 1);
                rr[e] = pR[base + cx]; gg[e] = pG[base + cx];
                bb[e] = pB[base + cx]; kk[e] = pK[base + cx];
            }
        }
        unsigned rg[4], bw[4];
#pragma unroll
        for (int e = 0; e < 4; ++e) {
            rg[e] = bf16rne(rr[e]) | (bf16rne(gg[e]) << 16);
            bw[e] = bf16rne(bb[e]) | (bf16rne(kk[e]) << 16);
        }
        int c = q << 2;
        *(uint4*)&s_vw[j][c]     = make_uint4(rg[0], bw[0], rg[1], bw[1]);
        *(uint4*)&s_vw[j][c + 2] = make_uint4(rg[2], bw[2], rg[3], bw[3]);
    }
    __syncthreads();

    // ---- stage 3: vertical 5-sum at clamped center -> variance -> weight ----
    for (int idx = tid; idx < VR * 9; idx += 256) {
        int j2 = idx / 9, q = idx - j2 * 9;
        int c  = q << 2;
        int gyc = min(max(y0 - 2 + j2, 0), H - 1);
        int js  = gyc - y0 + 2;
        int g0  = x0 - 2 + c;
        float as[4], aq[4];
        if (g0 >= 0 && g0 + 3 <= W - 1) {
            float4 acc0 = make_float4(0.f, 0.f, 0.f, 0.f);
            float4 acc1 = make_float4(0.f, 0.f, 0.f, 0.f);
#pragma unroll
            for (int r = 0; r < 5; ++r) {
                float4 va = *(const float4*)&s_su[js + r][c];
                float4 vb = *(const float4*)&s_su[js + r][c + 2];
                acc0.x += va.x; acc0.y += va.y; acc0.z += va.z; acc0.w += va.w;
                acc1.x += vb.x; acc1.y += vb.y; acc1.z += vb.z; acc1.w += vb.w;
            }
            as[0]=acc0.x; aq[0]=acc0.y; as[1]=acc0.z; aq[1]=acc0.w;
            as[2]=acc1.x; aq[2]=acc1.y; as[3]=acc1.z; aq[3]=acc1.w;
        } else {
#pragma unroll
            for (int e = 0; e < 4; ++e) {
                int is = min(max(g0 + e, 0), W - 1) - x0 + 2;
                float ss = 0.f, sq = 0.f;
#pragma unroll
                for (int r = 0; r < 5; ++r) {
                    float2 v = s_su[js + r][is];
                    ss += v.x; sq += v.y;
                }
                as[e] = ss; aq[e] = sq;
            }
        }
#pragma unroll
        for (int e = 0; e < 4; ++e) {
            float mean = as[e] * 0.04f;
            float msq  = aq[e] * 0.04f;
            float var  = fabsf(msq - mean * mean);
            volatile unsigned short* cw = (volatile unsigned short*)&s_vw[j2][c + e];
            float kv = __uint_as_float(((unsigned)cw[3]) << 16);      // k (bf16)
            float wv = __expf(-var * 64.0f * kv);
            cw[3] = (unsigned short)bf16rne(wv);                      // -> weight
        }
    }
    __syncthreads();

    // ---- spatial-falloff constants ----
    float t1[4], t4[4];
#pragma unroll
    for (int p = 0; p < 4; ++p) {
        float t = __expf(-2.56f * (1.0f - kc[p]));
        t1[p] = t;
        t4[p] = (t * t) * (t * t);
    }

    // ---- stage 4: 25-tap filter; b64 taps, factorized row sums ----
    float accR[4], accG[4], accB[4], accW[4];
#pragma unroll
    for (int p = 0; p < 4; ++p) { accR[p] = accG[p] = accB[p] = accW[p] = 0.f; }

#pragma unroll
    for (int r = 0; r < 8; ++r) {
        const uint2* row = &s_vw[pr0 + r][tx];   // single base, imm offsets
        uint2 c0 = row[0], c1 = row[1], c2 = row[2], c3 = row[3], c4 = row[4];
        float a0x = bf16lo(c0.x), a0y = bf16hi(c0.x), a0z = bf16lo(c0.y), a0w = bf16hi(c0.y);
        float a1x = bf16lo(c1.x), a1y = bf16hi(c1.x), a1z = bf16lo(c1.y), a1w = bf16hi(c1.y);
        float a2x = bf16lo(c2.x), a2y = bf16hi(c2.x), a2z = bf16lo(c2.y), a2w = bf16hi(c2.y);
        float a3x = bf16lo(c3.x), a3y = bf16hi(c3.x), a3z = bf16lo(c3.y), a3w = bf16hi(c3.y);
        float a4x = bf16lo(c4.x), a4y = bf16hi(c4.x), a4z = bf16lo(c4.y), a4w = bf16hi(c4.y);
        // partial sums by |dx|: S0 (dx=0), S1 (|dx|=1), S2 (|dx|=2)
        float S0w = a2w;
        float S0x = a2w * a2x, S0y = a2w * a2y, S0z = a2w * a2z;
        float S1w = a1w + a3w;
        float S1x = a1w * a1x + a3w * a3x;
        float S1y = a1w * a1y + a3w * a3y;
        float S1z = a1w * a1z + a3w * a3z;
        float S2w = a0w + a4w;
        float S2x = a0w * a0x + a4w * a4x;
        float S2y = a0w * a0y + a4w * a4y;
        float S2z = a0w * a0z + a4w * a4z;
#pragma unroll
        for (int p = 0; p < 4; ++p) {
            const int dy = r - 2 - p;            // compile-time after unroll
            if (dy < -2 || dy > 2) continue;
            const int ady = dy < 0 ? -dy : dy;
            float rw = S0w + t1[p] * S1w + t4[p] * S2w;
            float rx = S0x + t1[p] * S1x + t4[p] * S2x;
            float ry = S0y + t1[p] * S1y + t4[p] * S2y;
            float rz = S0z + t1[p] * S1z + t4[p] * S2z;
            if (ady == 0) {
                accR[p] += rx; accG[p] += ry; accB[p] += rz; accW[p] += rw;
            } else {
                float rf = (ady == 1) ? t1[p] : t4[p];
                accR[p] += rf * rx; accG[p] += rf * ry;
                accB[p] += rf * rz; accW[p] += rf * rw;
            }
        }
    }

    float* __restrict__ oR = out + ((size_t)(3*n + 0) << 20);
    float* __restrict__ oG = out + ((size_t)(3*n + 1) << 20);
    float* __restrict__ oB = out + ((size_t)(3*n + 2) << 20);
#pragma unroll
    for (int p = 0; p < 4; ++p) {
        uint2 cc = s_vw[pr0 + p + 2][tx + 2];        // center rgb (bf16)
        float cx_ = bf16lo(cc.x), cy_ = bf16hi(cc.x), cz_ = bf16lo(cc.y);
        float cb = 16.0f + kc[p] * (0.001f - 16.0f); // center boost
        accR[p] += cb * cx_;
        accG[p] += cb * cy_;
        accB[p] += cb * cz_;
        accW[p] += cb;
        float inv = __builtin_amdgcn_rcpf(accW[p]);
        int off = ((y0 + pr0 + p) << 10) + gx;
        oR[off] = cx_ + kc[p] * (accR[p] * inv - cx_);
        oG[off] = cy_ + kc[p] * (accG[p] * inv - cy_);
        oB[off] = cz_ + kc[p] * (accB[p] * inv - cz_);
    }
}

extern "C" void kernel_launch(void* const* d_in, const int* in_sizes, int n_in,
                              void* d_out, int out_size, void* d_ws, size_t ws_size,
                              hipStream_t stream) {
    const float* inp = (const float*)d_in[0];
    float* out = (float*)d_out;
    dim3 grid(W / TILE, H / TILE, 4);
    hipLaunchKernelGGL(kuwahara_kernel, grid, dim3(256), 0, stream, inp, out);
}

// Round 9
// 61.777 us; speedup vs baseline: 1.0436x; 1.0436x over previous
//
#include <hip/hip_runtime.h>

#define H 1024
#define W 1024
#define TILE 32
#define SR 40    // hsum rows: TILE + 8 (halo4)
#define SC 36    // hsum cols: TILE + 4
#define VR 36    // vw rows:   TILE + 4
#define VC 36    // vw cols:   TILE + 4

// LDS: s_su 40*36*8 = 11520 B + s_vw 36*36*16 = 20736 B -> 32256 B total.

__global__ __launch_bounds__(256)
void kuwahara_kernel(const float* __restrict__ inp, float* __restrict__ out) {
    __shared__ float2 s_su[SR][SC];   // (hsum luma, hsum luma^2), halo4 rows
    __shared__ float4 s_vw[VR][VC];   // (r, g, b, k->weight), edge-replicated

    const int tid = threadIdx.x;
    const int n  = blockIdx.z;
    const int y0 = blockIdx.y * TILE;
    const int x0 = blockIdx.x * TILE;

    const float* __restrict__ pR = inp + ((size_t)(4*n + 0) << 20);
    const float* __restrict__ pG = inp + ((size_t)(4*n + 1) << 20);
    const float* __restrict__ pB = inp + ((size_t)(4*n + 2) << 20);
    const float* __restrict__ pK = inp + ((size_t)(4*n + 3) << 20);

    const int tx  = tid & 31;   // column within tile
    const int tg  = tid >> 5;   // row-group: owns rows 4*tg .. 4*tg+3
    const int gx  = x0 + tx;
    const int pr0 = tg << 2;

    // ---- k at this thread's 4 output pixels (fp32 exact; L2-resident) ----
    float kc[4];
#pragma unroll
    for (int p = 0; p < 4; ++p)
        kc[p] = pK[((y0 + pr0 + p) << 10) + gx];

    // ---- stage 1A: fused luma + horizontal 5-sums, zero-redundancy loads ----
    // 10 lanes per row (one 4-px quad each); neighbor quad via __shfl_down.
    // 6 rows/wave, 24 rows/pass, 2 passes cover 40 halo rows.
    {
        const int lane = tid & 63;
        const int wid  = tid >> 6;
        const int rloc = lane / 10;            // 0..5 active, 6 idle
        const int qq   = lane - rloc * 10;     // quad index 0..9
#pragma unroll
        for (int pass = 0; pass < 2; ++pass) {
            int row = pass * 24 + wid * 6 + rloc;
            bool act = (rloc < 6) && (row < SR);
            float l0 = 0.f, l1 = 0.f, l2 = 0.f, l3 = 0.f;
            if (act) {
                int gy  = y0 - 4 + row;
                int cy  = min(max(gy, 0), H - 1);
                int gcs = x0 - 4 + (qq << 2);
                const int base = cy << 10;
                float rr[4], gg[4], bb[4];
                if (gcs >= 0 && gcs <= W - 4) {
                    float4 r4 = *(const float4*)(pR + base + gcs);
                    float4 g4 = *(const float4*)(pG + base + gcs);
                    float4 b4 = *(const float4*)(pB + base + gcs);
                    rr[0]=r4.x; rr[1]=r4.y; rr[2]=r4.z; rr[3]=r4.w;
                    gg[0]=g4.x; gg[1]=g4.y; gg[2]=g4.z; gg[3]=g4.w;
                    bb[0]=b4.x; bb[1]=b4.y; bb[2]=b4.z; bb[3]=b4.w;
                } else {
#pragma unroll
                    for (int e = 0; e < 4; ++e) {
                        int cx = min(max(gcs + e, 0), W - 1);
                        rr[e] = pR[base + cx]; gg[e] = pG[base + cx]; bb[e] = pB[base + cx];
                    }
                }
                bool rowIn = ((unsigned)gy < (unsigned)H);
                float lv[4];
#pragma unroll
                for (int e = 0; e < 4; ++e) {
                    bool colIn = ((unsigned)(gcs + e) < (unsigned)W);
                    lv[e] = (rowIn && colIn)
                        ? fmaf(0.2126f, rr[e], fmaf(0.7152f, gg[e], 0.0722f * bb[e]))
                        : 0.0f;               // zero pad rows AND cols
                }
                l0 = lv[0]; l1 = lv[1]; l2 = lv[2]; l3 = lv[3];
            }
            // neighbor quad's luma (same row: qq<=8 pulls from qq+1)
            float l4 = __shfl_down(l0, 1, 64);
            float l5 = __shfl_down(l1, 1, 64);
            float l6 = __shfl_down(l2, 1, 64);
            float l7 = __shfl_down(l3, 1, 64);
            if (act && qq < 9) {
                float s0 = ((l0 + l1) + (l2 + l3)) + l4;
                float s1 = s0 - l0 + l5;
                float s2 = s1 - l1 + l6;
                float s3 = s2 - l2 + l7;
                float m0=l0*l0, m1=l1*l1, m2=l2*l2, m3=l3*l3;
                float m4=l4*l4, m5=l5*l5, m6=l6*l6, m7=l7*l7;
                float u0 = ((m0 + m1) + (m2 + m3)) + m4;
                float u1 = u0 - m0 + m5;
                float u2 = u1 - m1 + m6;
                float u3 = u2 - m2 + m7;
                int c = qq << 2;
                *(float4*)&s_su[row][c]     = make_float4(s0, u0, s1, u1);
                *(float4*)&s_su[row][c + 2] = make_float4(s2, u2, s3, u3);
            }
        }
    }

    // ---- stage 1B: rgbk -> s_vw (fp32), edge-replicated ----
    for (int idx = tid; idx < VR * 9; idx += 256) {
        int j = idx / 9, q = idx - j * 9;
        int gy  = y0 - 2 + j;
        int cy  = min(max(gy, 0), H - 1);
        int gcs = x0 - 2 + (q << 2);
        const int base = cy << 10;
        if (gcs >= 0 && gcs <= W - 4) {
            float4 r4 = *(const float4*)(pR + base + gcs);
            float4 g4 = *(const float4*)(pG + base + gcs);
            float4 b4 = *(const float4*)(pB + base + gcs);
            float4 k4 = *(const float4*)(pK + base + gcs);
            int c = q << 2;
            s_vw[j][c+0] = make_float4(r4.x, g4.x, b4.x, k4.x);
            s_vw[j][c+1] = make_float4(r4.y, g4.y, b4.y, k4.y);
            s_vw[j][c+2] = make_float4(r4.z, g4.z, b4.z, k4.z);
            s_vw[j][c+3] = make_float4(r4.w, g4.w, b4.w, k4.w);
        } else {
#pragma unroll
            for (int e = 0; e < 4; ++e) {
                int cx = min(max(gcs + e, 0), W - 1);
                s_vw[j][(q << 2) + e] =
                    make_float4(pR[base + cx], pG[base + cx],
                                pB[base + cx], pK[base + cx]);
            }
        }
    }
    __syncthreads();

    // ---- stage 3: vertical 5-sum -> variance -> weight. 8-wide, ONE pass ----
    // 180 tasks: j2 in [0,36), q in [0,5); q<4 covers 8 cols, q==4 covers 4.
    if (tid < 180) {
        int j2 = tid / 5, q = tid - j2 * 5;
        int c  = q << 3;
        int nw = (q == 4) ? 4 : 8;                  // cols this task
        int gyc = min(max(y0 - 2 + j2, 0), H - 1);  // clamped window center row
        int js  = gyc - y0 + 2;
        int g0  = x0 - 2 + c;
        float as[8], aq[8];
        if (g0 >= 0 && g0 + nw - 1 <= W - 1) {      // x-interior: vector path
            float4 a0 = make_float4(0.f,0.f,0.f,0.f), a1 = a0, a2 = a0, a3 = a0;
#pragma unroll
            for (int r = 0; r < 5; ++r) {
                const float4* rp = (const float4*)&s_su[js + r][c];
                float4 v0 = rp[0], v1 = rp[1];
                a0.x += v0.x; a0.y += v0.y; a0.z += v0.z; a0.w += v0.w;
                a1.x += v1.x; a1.y += v1.y; a1.z += v1.z; a1.w += v1.w;
                if (nw == 8) {
                    float4 v2 = rp[2], v3 = rp[3];
                    a2.x += v2.x; a2.y += v2.y; a2.z += v2.z; a2.w += v2.w;
                    a3.x += v3.x; a3.y += v3.y; a3.z += v3.z; a3.w += v3.w;
                }
            }
            as[0]=a0.x; aq[0]=a0.y; as[1]=a0.z; aq[1]=a0.w;
            as[2]=a1.x; aq[2]=a1.y; as[3]=a1.z; aq[3]=a1.w;
            as[4]=a2.x; aq[4]=a2.y; as[5]=a2.z; aq[5]=a2.w;
            as[6]=a3.x; aq[6]=a3.y; as[7]=a3.z; aq[7]=a3.w;
        } else {                                    // x-border: clamped scalar
            for (int e = 0; e < nw; ++e) {
                int is = min(max(g0 + e, 0), W - 1) - x0 + 2;
                float ss = 0.f, sq = 0.f;
#pragma unroll
                for (int r = 0; r < 5; ++r) {
                    float2 v = s_su[js + r][is];
                    ss += v.x; sq += v.y;
                }
                as[e] = ss; aq[e] = sq;
            }
        }
        for (int e = 0; e < nw; ++e) {
            float mean = as[e] * 0.04f;
            float msq  = aq[e] * 0.04f;
            float var  = fabsf(msq - mean * mean);
            float kv   = s_vw[j2][c + e].w;          // k stashed in stage 1B
            s_vw[j2][c + e].w = __expf(-var * 64.0f * kv);
        }
    }
    __syncthreads();

    // ---- spatial-falloff constants (late, short live ranges) ----
    float t1[4], t4[4];
#pragma unroll
    for (int p = 0; p < 4; ++p) {
        float t = __expf(-2.56f * (1.0f - kc[p]));   // t^(dx^2+dy^2) base
        t1[p] = t;
        t4[p] = (t * t) * (t * t);
    }

    // ---- stage 4: 25-tap filter; factorized row sums shared across 4 px ----
    float accR[4], accG[4], accB[4], accW[4];
#pragma unroll
    for (int p = 0; p < 4; ++p) { accR[p] = accG[p] = accB[p] = accW[p] = 0.f; }

#pragma unroll
    for (int r = 0; r < 8; ++r) {
        const float4* row = &s_vw[pr0 + r][tx];      // single base, imm offsets
        float4 a0 = row[0], a1 = row[1], a2 = row[2], a3 = row[3], a4 = row[4];
        // partial sums by |dx|: S0 (dx=0), S1 (|dx|=1), S2 (|dx|=2)
        float S0w = a2.w;
        float S0x = a2.w * a2.x, S0y = a2.w * a2.y, S0z = a2.w * a2.z;
        float S1w = a1.w + a3.w;
        float S1x = a1.w * a1.x + a3.w * a3.x;
        float S1y = a1.w * a1.y + a3.w * a3.y;
        float S1z = a1.w * a1.z + a3.w * a3.z;
        float S2w = a0.w + a4.w;
        float S2x = a0.w * a0.x + a4.w * a4.x;
        float S2y = a0.w * a0.y + a4.w * a4.y;
        float S2z = a0.w * a0.z + a4.w * a4.z;
#pragma unroll
        for (int p = 0; p < 4; ++p) {
            const int dy = r - 2 - p;                // compile-time after unroll
            if (dy < -2 || dy > 2) continue;
            const int ady = dy < 0 ? -dy : dy;
            float rw = S0w + t1[p] * S1w + t4[p] * S2w;
            float rx = S0x + t1[p] * S1x + t4[p] * S2x;
            float ry = S0y + t1[p] * S1y + t4[p] * S2y;
            float rz = S0z + t1[p] * S1z + t4[p] * S2z;
            if (ady == 0) {
                accR[p] += rx; accG[p] += ry; accB[p] += rz; accW[p] += rw;
            } else {
                float rf = (ady == 1) ? t1[p] : t4[p];
                accR[p] += rf * rx; accG[p] += rf * ry;
                accB[p] += rf * rz; accW[p] += rf * rw;
            }
        }
    }

    float* __restrict__ oR = out + ((size_t)(3*n + 0) << 20);
    float* __restrict__ oG = out + ((size_t)(3*n + 1) << 20);
    float* __restrict__ oB = out + ((size_t)(3*n + 2) << 20);
#pragma unroll
    for (int p = 0; p < 4; ++p) {
        float4 cen = s_vw[pr0 + p + 2][tx + 2];      // center rgb from LDS
        float cb = 16.0f + kc[p] * (0.001f - 16.0f); // center boost
        accR[p] += cb * cen.x;
        accG[p] += cb * cen.y;
        accB[p] += cb * cen.z;
        accW[p] += cb;
        float inv = __builtin_amdgcn_rcpf(accW[p]);
        int off = ((y0 + pr0 + p) << 10) + gx;
        oR[off] = cen.x + kc[p] * (accR[p] * inv - cen.x);
        oG[off] = cen.y + kc[p] * (accG[p] * inv - cen.y);
        oB[off] = cen.z + kc[p] * (accB[p] * inv - cen.z);
    }
}

extern "C" void kernel_launch(void* const* d_in, const int* in_sizes, int n_in,
                              void* d_out, int out_size, void* d_ws, size_t ws_size,
                              hipStream_t stream) {
    const float* inp = (const float*)d_in[0];
    float* out = (float*)d_out;
    dim3 grid(W / TILE, H / TILE, 4);
    hipLaunchKernelGGL(kuwahara_kernel, grid, dim3(256), 0, stream, inp, out);
}

// Round 10
// 37.465 us; speedup vs baseline: 1.7209x; 1.6489x over previous
//
#include <hip/hip_runtime.h>

#define H 1024
#define W 1024
#define TILE 32
#define SR 40    // hsum rows: TILE + 8 (halo4)
#define SC 36    // hsum cols: TILE + 4
#define VR 36    // vw rows:   TILE + 4
#define VC 36    // vw cols:   TILE + 4

// LDS: s_su 40*36*8 = 11520 B + s_vw 36*36*16 = 20736 B -> 32256 B -> 5 blocks/CU.

__global__ __launch_bounds__(256)
void kuwahara_kernel(const float* __restrict__ inp, float* __restrict__ out) {
    __shared__ float2 s_su[SR][SC];   // (hsum luma, hsum luma^2), halo4 rows
    __shared__ float4 s_vw[VR][VC];   // (r, g, b, k->weight), edge-replicated

    const int tid = threadIdx.x;

    // ---- XCD-aware swizzle: each XCD owns 512 contiguous tiles (x-fastest) ----
    unsigned wg  = blockIdx.x;          // grid = 4096 linear blocks
    unsigned lin = (wg & 7u) * 512u + (wg >> 3);
    const int n  = lin >> 10;
    const int y0 = ((lin >> 5) & 31) * TILE;
    const int x0 = (lin & 31) * TILE;

    const float* __restrict__ pR = inp + ((size_t)(4*n + 0) << 20);
    const float* __restrict__ pG = inp + ((size_t)(4*n + 1) << 20);
    const float* __restrict__ pB = inp + ((size_t)(4*n + 2) << 20);
    const float* __restrict__ pK = inp + ((size_t)(4*n + 3) << 20);

    const int tx  = tid & 31;   // column within tile
    const int tg  = tid >> 5;   // row-group: owns rows 4*tg .. 4*tg+3
    const int gx  = x0 + tx;
    const int pr0 = tg << 2;

    // ---- k at this thread's 4 output pixels (fp32 exact; L1/L2-resident) ----
    float kc[4];
#pragma unroll
    for (int p = 0; p < 4; ++p)
        kc[p] = pK[((y0 + pr0 + p) << 10) + gx];

    // ---- stage 1 (fully fused, SINGLE load of rgbk per halo pixel):
    // luma + horizontal 5-sums via __shfl_down, AND s_vw fill from the same
    // registers. 10 lanes/row (one 4-px quad each); 6 rows/wave; 2 passes.
    {
        const int lane = tid & 63;
        const int wid  = tid >> 6;
        const int rloc = lane / 10;            // 0..5 active, 6 idle
        const int qq   = lane - rloc * 10;     // quad index 0..9
        const int gcs  = x0 - 4 + (qq << 2);
#pragma unroll
        for (int pass = 0; pass < 2; ++pass) {
            int row = pass * 24 + wid * 6 + rloc;
            bool act = (rloc < 6) && (row < SR);
            bool vwrow = act && (row >= 2) && (row < SR - 2);
            float l0 = 0.f, l1 = 0.f, l2 = 0.f, l3 = 0.f;
            float rr[4], gg[4], bb[4], kk[4];
            if (act) {
                int gy = y0 - 4 + row;
                int cy = min(max(gy, 0), H - 1);
                const int base = cy << 10;
                if (gcs >= 0 && gcs <= W - 4) {         // x-interior: vector
                    float4 r4 = *(const float4*)(pR + base + gcs);
                    float4 g4 = *(const float4*)(pG + base + gcs);
                    float4 b4 = *(const float4*)(pB + base + gcs);
                    rr[0]=r4.x; rr[1]=r4.y; rr[2]=r4.z; rr[3]=r4.w;
                    gg[0]=g4.x; gg[1]=g4.y; gg[2]=g4.z; gg[3]=g4.w;
                    bb[0]=b4.x; bb[1]=b4.y; bb[2]=b4.z; bb[3]=b4.w;
                    if (vwrow) {
                        float4 k4 = *(const float4*)(pK + base + gcs);
                        kk[0]=k4.x; kk[1]=k4.y; kk[2]=k4.z; kk[3]=k4.w;
                    }
                } else {                                 // x-border: clamped
#pragma unroll
                    for (int e = 0; e < 4; ++e) {
                        int cx = min(max(gcs + e, 0), W - 1);
                        rr[e] = pR[base + cx]; gg[e] = pG[base + cx];
                        bb[e] = pB[base + cx];
                        kk[e] = vwrow ? pK[base + cx] : 0.f;
                    }
                }
                bool rowIn = ((unsigned)gy < (unsigned)H);
                float lv[4];
#pragma unroll
                for (int e = 0; e < 4; ++e) {
                    bool colIn = ((unsigned)(gcs + e) < (unsigned)W);
                    lv[e] = (rowIn && colIn)
                        ? fmaf(0.2126f, rr[e], fmaf(0.7152f, gg[e], 0.0722f * bb[e]))
                        : 0.0f;                          // zero pad rows AND cols
                }
                l0 = lv[0]; l1 = lv[1]; l2 = lv[2]; l3 = lv[3];
            }
            // neighbor quad's luma (same row: qq<=8 pulls from qq+1)
            float l4 = __shfl_down(l0, 1, 64);
            float l5 = __shfl_down(l1, 1, 64);
            float l6 = __shfl_down(l2, 1, 64);
            float l7 = __shfl_down(l3, 1, 64);
            if (act && qq < 9) {
                float s0 = ((l0 + l1) + (l2 + l3)) + l4;
                float s1 = s0 - l0 + l5;
                float s2 = s1 - l1 + l6;
                float s3 = s2 - l2 + l7;
                float m0=l0*l0, m1=l1*l1, m2=l2*l2, m3=l3*l3;
                float m4=l4*l4, m5=l5*l5, m6=l6*l6, m7=l7*l7;
                float u0 = ((m0 + m1) + (m2 + m3)) + m4;
                float u1 = u0 - m0 + m5;
                float u2 = u1 - m1 + m6;
                float u3 = u2 - m2 + m7;
                int c = qq << 2;
                *(float4*)&s_su[row][c]     = make_float4(s0, u0, s1, u1);
                *(float4*)&s_su[row][c + 2] = make_float4(s2, u2, s3, u3);
            }
            if (vwrow) {                                 // s_vw from SAME regs
#pragma unroll
                for (int e = 0; e < 4; ++e) {
                    int iv = (qq << 2) + e - 2;
                    if ((unsigned)iv < (unsigned)VC)
                        s_vw[row - 2][iv] = make_float4(rr[e], gg[e], bb[e], kk[e]);
                }
            }
        }
    }
    __syncthreads();

    // ---- stage 3: vertical 5-sum -> variance -> weight. 2-wide tasks ----
    // 648 tasks: j2 in [0,36), q in [0,18); 16 consecutive lanes read 256 B
    // contiguous per row -> bank-conflict-free pattern.
    for (int idx = tid; idx < VR * 18; idx += 256) {
        int j2 = idx / 18, q = idx - j2 * 18;
        int c  = q << 1;
        int gyc = min(max(y0 - 2 + j2, 0), H - 1);  // clamped window center row
        int js  = gyc - y0 + 2;
        int g0  = x0 - 2 + c;                       // unclamped center col (e=0)
        float s_a, u_a, s_b, u_b;
        if (g0 >= 0 && g0 + 1 <= W - 1) {           // both cols interior
            float4 acc = make_float4(0.f, 0.f, 0.f, 0.f);
#pragma unroll
            for (int r = 0; r < 5; ++r) {
                float4 v = *(const float4*)&s_su[js + r][c];
                acc.x += v.x; acc.y += v.y; acc.z += v.z; acc.w += v.w;
            }
            s_a = acc.x; u_a = acc.y; s_b = acc.z; u_b = acc.w;
        } else {                                    // x-border: clamped scalar
            float sv[2], uv[2];
#pragma unroll
            for (int e = 0; e < 2; ++e) {
                int is = min(max(g0 + e, 0), W - 1) - x0 + 2;
                float ss = 0.f, sq = 0.f;
#pragma unroll
                for (int r = 0; r < 5; ++r) {
                    float2 v = s_su[js + r][is];
                    ss += v.x; sq += v.y;
                }
                sv[e] = ss; uv[e] = sq;
            }
            s_a = sv[0]; u_a = uv[0]; s_b = sv[1]; u_b = uv[1];
        }
        {
            float mean = s_a * 0.04f, msq = u_a * 0.04f;
            float var  = fabsf(msq - mean * mean);
            float kv   = s_vw[j2][c].w;
            s_vw[j2][c].w = __expf(-var * 64.0f * kv);
        }
        {
            float mean = s_b * 0.04f, msq = u_b * 0.04f;
            float var  = fabsf(msq - mean * mean);
            float kv   = s_vw[j2][c + 1].w;
            s_vw[j2][c + 1].w = __expf(-var * 64.0f * kv);
        }
    }
    __syncthreads();

    // ---- spatial-falloff constants (late, short live ranges) ----
    float t1[4], t4[4];
#pragma unroll
    for (int p = 0; p < 4; ++p) {
        float t = __expf(-2.56f * (1.0f - kc[p]));   // t^(dx^2+dy^2) base
        t1[p] = t;
        t4[p] = (t * t) * (t * t);
    }

    // ---- stage 4: 25-tap filter; factorized row sums shared across 4 px ----
    float accR[4], accG[4], accB[4], accW[4];
#pragma unroll
    for (int p = 0; p < 4; ++p) { accR[p] = accG[p] = accB[p] = accW[p] = 0.f; }

#pragma unroll
    for (int r = 0; r < 8; ++r) {
        const float4* row = &s_vw[pr0 + r][tx];      // single base, imm offsets
        float4 a0 = row[0], a1 = row[1], a2 = row[2], a3 = row[3], a4 = row[4];
        // partial sums by |dx|: S0 (dx=0), S1 (|dx|=1), S2 (|dx|=2)
        float S0w = a2.w;
        float S0x = a2.w * a2.x, S0y = a2.w * a2.y, S0z = a2.w * a2.z;
        float S1w = a1.w + a3.w;
        float S1x = a1.w * a1.x + a3.w * a3.x;
        float S1y = a1.w * a1.y + a3.w * a3.y;
        float S1z = a1.w * a1.z + a3.w * a3.z;
        float S2w = a0.w + a4.w;
        float S2x = a0.w * a0.x + a4.w * a4.x;
        float S2y = a0.w * a0.y + a4.w * a4.y;
        float S2z = a0.w * a0.z + a4.w * a4.z;
#pragma unroll
        for (int p = 0; p < 4; ++p) {
            const int dy = r - 2 - p;                // compile-time after unroll
            if (dy < -2 || dy > 2) continue;
            const int ady = dy < 0 ? -dy : dy;
            float rw = S0w + t1[p] * S1w + t4[p] * S2w;
            float rx = S0x + t1[p] * S1x + t4[p] * S2x;
            float ry = S0y + t1[p] * S1y + t4[p] * S2y;
            float rz = S0z + t1[p] * S1z + t4[p] * S2z;
            if (ady == 0) {
                accR[p] += rx; accG[p] += ry; accB[p] += rz; accW[p] += rw;
            } else {
                float rf = (ady == 1) ? t1[p] : t4[p];
                accR[p] += rf * rx; accG[p] += rf * ry;
                accB[p] += rf * rz; accW[p] += rf * rw;
            }
        }
    }

    float* __restrict__ oR = out + ((size_t)(3*n + 0) << 20);
    float* __restrict__ oG = out + ((size_t)(3*n + 1) << 20);
    float* __restrict__ oB = out + ((size_t)(3*n + 2) << 20);
#pragma unroll
    for (int p = 0; p < 4; ++p) {
        float4 cen = s_vw[pr0 + p + 2][tx + 2];      // center rgb from LDS
        float cb = 16.0f + kc[p] * (0.001f - 16.0f); // center boost
        accR[p] += cb * cen.x;
        accG[p] += cb * cen.y;
        accB[p] += cb * cen.z;
        accW[p] += cb;
        float inv = __builtin_amdgcn_rcpf(accW[p]);
        int off = ((y0 + pr0 + p) << 10) + gx;
        oR[off] = cen.x + kc[p] * (accR[p] * inv - cen.x);
        oG[off] = cen.y + kc[p] * (accG[p] * inv - cen.y);
        oB[off] = cen.z + kc[p] * (accB[p] * inv - cen.z);
    }
}

extern "C" void kernel_launch(void* const* d_in, const int* in_sizes, int n_in,
                              void* d_out, int out_size, void* d_ws, size_t ws_size,
                              hipStream_t stream) {
    const float* inp = (const float*)d_in[0];
    float* out = (float*)d_out;
    hipLaunchKernelGGL(kuwahara_kernel, dim3(4096), dim3(256), 0, stream, inp, out);
}